// Round 9
// baseline (352.288 us; speedup 1.0000x reference)
//
#include <hip/hip_runtime.h>

#define N 4096
#define CAP 128

// ===========================================================================
// K1a: dis row-collect -> r16[row], candidate (d,j) lists. One block per row.
// ===========================================================================
__global__ __launch_bounds__(256) void K1a(const float* __restrict__ dis,
                                           float* __restrict__ r16,
                                           float* __restrict__ cand_d, int* __restrict__ cand_j,
                                           int* __restrict__ cntc, float* __restrict__ Trow) {
  __shared__ int lcnt;
  __shared__ float lval[CAP];
  __shared__ int lidx[CAP];
  int row = blockIdx.x, t = threadIdx.x;
  const float4* dp = (const float4*)(dis + (size_t)row * N);
  float T = 0.12f;
  int c = 0;
  for (int iter = 0; iter < 24; iter++) {
    if (t == 0) lcnt = 0;
    __syncthreads();
#pragma unroll
    for (int q = 0; q < 4; q++) {
      float4 d = dp[q * 256 + t];
      int jb = (q * 256 + t) << 2;
      if (d.x <= T) { int p = atomicAdd(&lcnt, 1); if (p < CAP) { lval[p] = d.x; lidx[p] = jb + 0; } }
      if (d.y <= T) { int p = atomicAdd(&lcnt, 1); if (p < CAP) { lval[p] = d.y; lidx[p] = jb + 1; } }
      if (d.z <= T) { int p = atomicAdd(&lcnt, 1); if (p < CAP) { lval[p] = d.z; lidx[p] = jb + 2; } }
      if (d.w <= T) { int p = atomicAdd(&lcnt, 1); if (p < CAP) { lval[p] = d.w; lidx[p] = jb + 3; } }
    }
    __syncthreads();
    c = lcnt;
    __syncthreads();
    if (c >= 16 && c <= CAP) break;
    T = (c < 16) ? T * 2.0f : T * 0.5f;
  }
  // exact 16th smallest among candidates (ties by index -> unique rank 15)
  if (t < c) {
    float v = lval[t];
    int less = 0;
    for (int j = 0; j < c; j++) {
      float u = lval[j];
      less += (u < v) || (u == v && j < t);
    }
    if (less == 15) r16[row] = v;
  }
  for (int k = t; k < c; k += 256) {
    cand_d[row * CAP + k] = lval[k];
    cand_j[row * CAP + k] = lidx[k];
  }
  if (t == 0) { cntc[row] = c; Trow[row] = T; }
}

// ===========================================================================
// K1b: adj -> cnt1/nbr1 (nz(i) = { j : adj[j][i] != 0 }).
// ===========================================================================
__global__ __launch_bounds__(256) void K1b(const float4* __restrict__ adj4,
                                           int* __restrict__ cnt1, int* __restrict__ nbr1) {
  int chunk = blockIdx.x, t = threadIdx.x;   // 1024 chunks x 4096 float4
#pragma unroll
  for (int q = 0; q < 16; q++) {
    int k = chunk * 4096 + q * 256 + t;
    float4 a = adj4[k];
    int base = k << 2;
    int j  = base >> 12;       // adj row
    int i0 = base & (N - 1);   // adj col (output row)
    if (a.x != 0.f) { int p = atomicAdd(&cnt1[i0 + 0], 1); if (p < CAP) nbr1[(i0 + 0) * CAP + p] = j; }
    if (a.y != 0.f) { int p = atomicAdd(&cnt1[i0 + 1], 1); if (p < CAP) nbr1[(i0 + 1) * CAP + p] = j; }
    if (a.z != 0.f) { int p = atomicAdd(&cnt1[i0 + 2], 1); if (p < CAP) nbr1[(i0 + 2) * CAP + p] = j; }
    if (a.w != 0.f) { int p = atomicAdd(&cnt1[i0 + 3], 1); if (p < CAP) nbr1[(i0 + 3) * CAP + p] = j; }
  }
}

// ===========================================================================
// K1c: Y0 = features @ W0, 16 rows per block.
// ===========================================================================
__global__ __launch_bounds__(256) void K1c(const float* __restrict__ X, const float* __restrict__ W0,
                                           float* __restrict__ Y0) {
  __shared__ float xs[16][128];
  int t = threadIdx.x;
  int r0 = blockIdx.x * 16;
  int col = t & 127, half = t >> 7;
#pragma unroll
  for (int q = 0; q < 8; q++) xs[q * 2 + half][col] = X[(size_t)(r0 + q * 2 + half) * 128 + col];
  __syncthreads();
  float acc[8] = {0.f, 0.f, 0.f, 0.f, 0.f, 0.f, 0.f, 0.f};
#pragma unroll 4
  for (int k = 0; k < 128; k++) {
    float wk = W0[k * 128 + col];
#pragma unroll
    for (int r = 0; r < 8; r++) acc[r] = fmaf(xs[half * 8 + r][k], wk, acc[r]);
  }
#pragma unroll
  for (int r = 0; r < 8; r++) Y0[(size_t)(r0 + half * 8 + r) * 128 + col] = acc[r];
}

// ===========================================================================
// K2: block 0 = exact median (radix select, parallel bin scan);
//     blocks [1,2049) = SpMM+relu, 2 rows/block:
//     h1[i] = relu(dinv_i*(dinv_i*Y0[i] + sum_j dinv_j*Y0[j]) + b0)
// ===========================================================================
__global__ __launch_bounds__(256) void K2(const float* __restrict__ r16, float* __restrict__ scal,
                                          const float* __restrict__ Y0, const int* __restrict__ cnt1,
                                          const int* __restrict__ nbr1, const float* __restrict__ b0,
                                          float* __restrict__ h1) {
  int b = blockIdx.x, t = threadIdx.x;
  if (b == 0) {
    __shared__ unsigned int keys[N];
    __shared__ int hist[256];
    __shared__ int wsum4[4];
    __shared__ unsigned int s_prefix;
    __shared__ int s_rank;
#pragma unroll
    for (int q = 0; q < 16; q++) keys[q * 256 + t] = __float_as_uint(r16[q * 256 + t]);
    __syncthreads();
    float res[2];
#pragma unroll
    for (int sel = 0; sel < 2; sel++) {
      if (t == 0) { s_rank = 2047 + sel; s_prefix = 0u; }
      __syncthreads();
      unsigned int mask = 0u;
      for (int shift = 24; shift >= 0; shift -= 8) {
        hist[t] = 0;
        __syncthreads();
        unsigned int prefix = s_prefix;
#pragma unroll
        for (int q = 0; q < 16; q++) {
          unsigned int k = keys[q * 256 + t];
          if ((k & mask) == prefix) atomicAdd(&hist[(k >> shift) & 255], 1);
        }
        __syncthreads();
        int r = s_rank;
        int ht = hist[t];
        int x = ht;
#pragma unroll
        for (int s = 1; s < 64; s <<= 1) {
          int y = __shfl_up(x, s, 64);
          if ((t & 63) >= s) x += y;
        }
        if ((t & 63) == 63) wsum4[t >> 6] = x;
        __syncthreads();
        int off = 0;
#pragma unroll
        for (int w = 0; w < 4; w++) off += (w < (t >> 6)) ? wsum4[w] : 0;
        int incl = x + off, excl = incl - ht;
        if (r >= excl && r < incl) {          // exactly one thread
          s_prefix = prefix | ((unsigned int)t << shift);
          s_rank = r - excl;
        }
        __syncthreads();
        mask |= (255u << shift);
      }
      res[sel] = __uint_as_float(s_prefix);
      __syncthreads();
    }
    if (t == 0) {
      float dcut = 0.5f * (res[0] + res[1]);
      scal[0] = dcut;
      scal[1] = 1.0f / dcut;
    }
  } else {
    int row = 2 * (b - 1) + (t >> 7);
    int col = t & 127;
    int ci = min(cnt1[row], CAP);
    float dvi = 1.0f / sqrtf((float)ci + 1.0f);
    const int* lst = nbr1 + row * CAP;
    float acc = dvi * Y0[(size_t)row * 128 + col];
    for (int q = 0; q < ci; q++) {
      int j = lst[q];
      float dvj = 1.0f / sqrtf((float)min(cnt1[j], CAP) + 1.0f);
      acc += dvj * Y0[(size_t)j * 128 + col];
    }
    h1[(size_t)row * 128 + col] = fmaxf(dvi * acc + b0[col], 0.0f);
  }
}

// ===========================================================================
// K3: Y1 = h1 @ W1, 16 rows per block.
// ===========================================================================
__global__ __launch_bounds__(256) void K3(const float* __restrict__ X, const float* __restrict__ W1,
                                          float* __restrict__ Y1) {
  __shared__ float xs[16][128];
  int t = threadIdx.x;
  int r0 = blockIdx.x * 16;
  int col = t & 127, half = t >> 7;
#pragma unroll
  for (int q = 0; q < 8; q++) xs[q * 2 + half][col] = X[(size_t)(r0 + q * 2 + half) * 128 + col];
  __syncthreads();
  float acc[8] = {0.f, 0.f, 0.f, 0.f, 0.f, 0.f, 0.f, 0.f};
#pragma unroll 4
  for (int k = 0; k < 128; k++) {
    float wk = W1[k * 128 + col];
#pragma unroll
    for (int r = 0; r < 8; r++) acc[r] = fmaf(xs[half * 8 + r][k], wk, acc[r]);
  }
#pragma unroll
  for (int r = 0; r < 8; r++) Y1[(size_t)(r0 + half * 8 + r) * 128 + col] = acc[r];
}

// ===========================================================================
// K4: SpMM (no relu) -> h, plus row norms. 2 rows/block.
// ===========================================================================
__global__ __launch_bounds__(256) void K4(const float* __restrict__ Y1, const int* __restrict__ cnt1,
                                          const int* __restrict__ nbr1, const float* __restrict__ b1,
                                          float* __restrict__ hbuf, float* __restrict__ hnorm) {
  __shared__ float red[4];
  int b = blockIdx.x, t = threadIdx.x;
  int row = 2 * b + (t >> 7);
  int col = t & 127;
  int ci = min(cnt1[row], CAP);
  float dvi = 1.0f / sqrtf((float)ci + 1.0f);
  const int* lst = nbr1 + row * CAP;
  float acc = dvi * Y1[(size_t)row * 128 + col];
  for (int q = 0; q < ci; q++) {
    int j = lst[q];
    float dvj = 1.0f / sqrtf((float)min(cnt1[j], CAP) + 1.0f);
    acc += dvj * Y1[(size_t)j * 128 + col];
  }
  float h = dvi * acc + b1[col];
  hbuf[(size_t)row * 128 + col] = h;
  float ss = h * h;
#pragma unroll
  for (int s = 32; s; s >>= 1) ss += __shfl_xor(ss, s, 64);
  if ((t & 63) == 0) red[t >> 6] = ss;
  __syncthreads();
  if (t == 0)   hnorm[row] = sqrtf(red[0] + red[1]);
  if (t == 128) hnorm[row] = sqrtf(red[2] + red[3]);
}

// ===========================================================================
// K5: per row: filter candidates by (d>0 && d<=dcut), s_d = 0.5*exp(-8(d/dcut)^2),
//     s1 = 0.5*relu(cos(h_i,h_j)); write s[i,j] directly (outputs pre-zeroed);
//     save (j,val) lists + deg[i] for K6's s_norm scatter.
//     Slow path (never taken on this data): rescan dis row if Trow < dcut.
// ===========================================================================
__global__ __launch_bounds__(256) void K5(const float* __restrict__ dis, const float* __restrict__ scal,
                                          const float* __restrict__ cand_d, const int* __restrict__ cand_j,
                                          const int* __restrict__ cntc, const float* __restrict__ Trow,
                                          const float* __restrict__ hbuf, const float* __restrict__ hnorm,
                                          float* __restrict__ vals, int* __restrict__ jdx,
                                          int* __restrict__ cnt2, float* __restrict__ deg,
                                          float* __restrict__ s_out) {
  __shared__ float cd[CAP];
  __shared__ int cj[CAP];
  __shared__ float sdv[CAP];
  __shared__ int sj[CAP];
  __shared__ int ccnt, scnt;
  __shared__ float hi[128];
  __shared__ float wred[4];
  int row = blockIdx.x, t = threadIdx.x;
  int wv = t >> 6, ln = t & 63;
  float dcut = scal[0];
  if (t == 0) { scnt = 0; ccnt = 0; }
  if (t < 128) hi[t] = hbuf[(size_t)row * 128 + t];
  __syncthreads();
  int c1;
  if (Trow[row] >= dcut) {
    c1 = cntc[row];
    for (int k = t; k < c1; k += 256) { cd[k] = cand_d[row * CAP + k]; cj[k] = cand_j[row * CAP + k]; }
  } else {
    const float4* dp = (const float4*)(dis + (size_t)row * N);
#pragma unroll
    for (int q = 0; q < 4; q++) {
      float4 d = dp[q * 256 + t];
      int jb = (q * 256 + t) << 2;
      if (d.x <= dcut) { int p = atomicAdd(&ccnt, 1); if (p < CAP) { cd[p] = d.x; cj[p] = jb + 0; } }
      if (d.y <= dcut) { int p = atomicAdd(&ccnt, 1); if (p < CAP) { cd[p] = d.y; cj[p] = jb + 1; } }
      if (d.z <= dcut) { int p = atomicAdd(&ccnt, 1); if (p < CAP) { cd[p] = d.z; cj[p] = jb + 2; } }
      if (d.w <= dcut) { int p = atomicAdd(&ccnt, 1); if (p < CAP) { cd[p] = d.w; cj[p] = jb + 3; } }
    }
    __syncthreads();
    c1 = min(ccnt, CAP);
  }
  __syncthreads();
  if (t < c1) {
    float d = cd[t];
    if (d > 0.f && d <= dcut) {
      float r = d / dcut;
      int p = atomicAdd(&scnt, 1);
      sdv[p] = 0.5f * expf(-8.0f * r * r);
      sj[p] = cj[t];
    }
  }
  __syncthreads();
  int c2 = scnt;
  float ni = hnorm[row];
  float wsum = 0.f;
  for (int idx = wv; idx < c2; idx += 4) {
    int j = sj[idx];
    const float* hj = hbuf + (size_t)j * 128;
    float p = hi[ln] * hj[ln] + hi[ln + 64] * hj[ln + 64];
#pragma unroll
    for (int s = 32; s; s >>= 1) p += __shfl_xor(p, s, 64);
    if (ln == 0) {
      float s1 = fmaxf(p / (ni * hnorm[j] + 1e-8f), 0.f);
      float v = sdv[idx] + 0.5f * s1;
      s_out[(size_t)row * N + j] = v;          // second output, pre-zeroed
      vals[row * CAP + idx] = v;
      jdx[row * CAP + idx] = j;
      wsum += v;
    }
  }
  if (ln == 0) wred[wv] = wsum;
  __syncthreads();
  if (t == 0) {
    deg[row] = wred[0] + wred[1] + wred[2] + wred[3];
    cnt2[row] = c2;
  }
}

// ===========================================================================
// K6: scatter s_norm[i,j] = dinv_i * dinv_j * v (outputs pre-zeroed).
// ===========================================================================
__global__ __launch_bounds__(128) void K6(const float* __restrict__ vals, const int* __restrict__ jdx,
                                          const int* __restrict__ cnt2, const float* __restrict__ deg,
                                          float* __restrict__ s_norm_out) {
  int row = blockIdx.x, t = threadIdx.x;
  int c2 = cnt2[row];
  if (t < c2) {
    float dgi = deg[row];
    float di = (dgi > 0.f) ? (1.0f / sqrtf(dgi)) : 0.f;
    int j = jdx[row * CAP + t];
    float v = vals[row * CAP + t];
    float dgj = deg[j];
    float dj = (dgj > 0.f) ? (1.0f / sqrtf(dgj)) : 0.f;
    s_norm_out[(size_t)row * N + j] = di * dj * v;
  }
}

extern "C" void kernel_launch(void* const* d_in, const int* in_sizes, int n_in,
                              void* d_out, int out_size, void* d_ws, size_t ws_size,
                              hipStream_t stream) {
  const float* features = (const float*)d_in[0];
  const float* adj      = (const float*)d_in[1];
  const float* dis      = (const float*)d_in[2];
  const float* W0       = (const float*)d_in[3];
  const float* b0       = (const float*)d_in[4];
  const float* W1       = (const float*)d_in[5];
  const float* b1       = (const float*)d_in[6];
  float* out    = (float*)d_out;              // s_norm
  float* s_half = out + (size_t)N * N;        // s

  char* ws = (char*)d_ws;
  float* r16   = (float*)(ws + 0);            // 16KB
  int*   cnt1  = (int*)  (ws + 16384);        // 16KB
  int*   cntc  = (int*)  (ws + 32768);        // 16KB
  float* Trow  = (float*)(ws + 49152);        // 16KB
  float* deg   = (float*)(ws + 65536);        // 16KB
  int*   cnt2  = (int*)  (ws + 81920);        // 16KB
  float* scal  = (float*)(ws + 98304);        // small
  float* hnorm = (float*)(ws + 114688);       // 16KB
  int*   nbr1  = (int*)  (ws + 131072 + 0 * 2097152);
  float* cand_dv=(float*)(ws + 131072 + 1 * 2097152);
  int*   cand_j= (int*)  (ws + 131072 + 2 * 2097152);
  float* vals  = (float*)(ws + 131072 + 3 * 2097152);
  int*   jdx   = (int*)  (ws + 131072 + 4 * 2097152);
  float* Y0    = (float*)(ws + 131072 + 5 * 2097152);
  float* h1    = (float*)(ws + 131072 + 6 * 2097152);
  float* Y1    = (float*)(ws + 131072 + 7 * 2097152);
  float* hbuf  = (float*)(ws + 131072 + 8 * 2097152);

  // zero both dense outputs via the runtime fill path (~6 TB/s) + cnt1
  hipMemsetAsync(out, 0, (size_t)2 * N * N * sizeof(float), stream);
  hipMemsetAsync(cnt1, 0, N * sizeof(int), stream);

  K1a<<<4096, 256, 0, stream>>>(dis, r16, cand_dv, cand_j, cntc, Trow);
  K1b<<<1024, 256, 0, stream>>>((const float4*)adj, cnt1, nbr1);
  K1c<<<256, 256, 0, stream>>>(features, W0, Y0);
  K2<<<2049, 256, 0, stream>>>(r16, scal, Y0, cnt1, nbr1, b0, h1);
  K3<<<256, 256, 0, stream>>>(h1, W1, Y1);
  K4<<<2048, 256, 0, stream>>>(Y1, cnt1, nbr1, b1, hbuf, hnorm);
  K5<<<4096, 256, 0, stream>>>(dis, scal, cand_dv, cand_j, cntc, Trow,
                               hbuf, hnorm, vals, jdx, cnt2, deg, s_half);
  K6<<<4096, 128, 0, stream>>>(vals, jdx, cnt2, deg, out);
}

// Round 11
// 337.912 us; speedup vs baseline: 1.0425x; 1.0425x over previous
//
#include <hip/hip_runtime.h>

#define N 4096
#define CAP 128

// ===========================================================================
// K1 (partitioned; compute-tail first so it overlaps the streaming phases):
//   blocks [0,256)       : Y0 = features @ W0   (16 rows/block)
//   blocks [256,1280)    : adj -> cnt1/nbr1 (nz(i) = { j : adj[j][i] != 0 })
//   blocks [1280,5376)   : dis row-collect -> r16[row], candidate (d,j) lists
// ===========================================================================
__global__ __launch_bounds__(256) void K1(const float* __restrict__ dis,
                                          const float4* __restrict__ adj4,
                                          const float* __restrict__ X,
                                          const float* __restrict__ W0,
                                          int* __restrict__ cnt1, int* __restrict__ nbr1,
                                          float* __restrict__ r16,
                                          float* __restrict__ cand_d, int* __restrict__ cand_j,
                                          int* __restrict__ cntc, float* __restrict__ Trow,
                                          float* __restrict__ Y0) {
  int b = blockIdx.x, t = threadIdx.x;
  if (b < 256) {
    // ---- Y0 = X @ W0, 16 rows per block ----
    __shared__ float xs[16][128];
    int r0 = b * 16;
    int col = t & 127, half = t >> 7;
#pragma unroll
    for (int q = 0; q < 8; q++) xs[q * 2 + half][col] = X[(size_t)(r0 + q * 2 + half) * 128 + col];
    __syncthreads();
    float acc[8] = {0.f, 0.f, 0.f, 0.f, 0.f, 0.f, 0.f, 0.f};
#pragma unroll 4
    for (int k = 0; k < 128; k++) {
      float wk = W0[k * 128 + col];
#pragma unroll
      for (int r = 0; r < 8; r++) acc[r] = fmaf(xs[half * 8 + r][k], wk, acc[r]);
    }
#pragma unroll
    for (int r = 0; r < 8; r++) Y0[(size_t)(r0 + half * 8 + r) * 128 + col] = acc[r];
  } else if (b < 1280) {
    // ---- adjacency build ----
    int chunk = b - 256;   // 1024 chunks x 4096 float4
#pragma unroll
    for (int q = 0; q < 16; q++) {
      int k = chunk * 4096 + q * 256 + t;
      float4 a = adj4[k];
      int base = k << 2;
      int j  = base >> 12;       // adj row
      int i0 = base & (N - 1);   // adj col (output row)
      if (a.x != 0.f) { int p = atomicAdd(&cnt1[i0 + 0], 1); if (p < CAP) nbr1[(i0 + 0) * CAP + p] = j; }
      if (a.y != 0.f) { int p = atomicAdd(&cnt1[i0 + 1], 1); if (p < CAP) nbr1[(i0 + 1) * CAP + p] = j; }
      if (a.z != 0.f) { int p = atomicAdd(&cnt1[i0 + 2], 1); if (p < CAP) nbr1[(i0 + 2) * CAP + p] = j; }
      if (a.w != 0.f) { int p = atomicAdd(&cnt1[i0 + 3], 1); if (p < CAP) nbr1[(i0 + 3) * CAP + p] = j; }
    }
  } else {
    // ---- row-collect: all (d,j) with d <= T (retry T if out of [16,CAP]) ----
    __shared__ int lcnt;
    __shared__ float lval[CAP];
    __shared__ int lidx[CAP];
    int row = b - 1280;
    const float4* dp = (const float4*)(dis + (size_t)row * N);
    float T = 0.12f;
    int c = 0;
    for (int iter = 0; iter < 24; iter++) {
      if (t == 0) lcnt = 0;
      __syncthreads();
#pragma unroll
      for (int q = 0; q < 4; q++) {
        float4 d = dp[q * 256 + t];
        int jb = (q * 256 + t) << 2;
        if (d.x <= T) { int p = atomicAdd(&lcnt, 1); if (p < CAP) { lval[p] = d.x; lidx[p] = jb + 0; } }
        if (d.y <= T) { int p = atomicAdd(&lcnt, 1); if (p < CAP) { lval[p] = d.y; lidx[p] = jb + 1; } }
        if (d.z <= T) { int p = atomicAdd(&lcnt, 1); if (p < CAP) { lval[p] = d.z; lidx[p] = jb + 2; } }
        if (d.w <= T) { int p = atomicAdd(&lcnt, 1); if (p < CAP) { lval[p] = d.w; lidx[p] = jb + 3; } }
      }
      __syncthreads();
      c = lcnt;
      __syncthreads();
      if (c >= 16 && c <= CAP) break;
      T = (c < 16) ? T * 2.0f : T * 0.5f;
    }
    // exact 16th smallest among candidates (ties by index -> unique rank 15)
    if (t < c) {
      float v = lval[t];
      int less = 0;
      for (int j = 0; j < c; j++) {
        float u = lval[j];
        less += (u < v) || (u == v && j < t);
      }
      if (less == 15) r16[row] = v;
    }
    for (int k = t; k < c; k += 256) {
      cand_d[row * CAP + k] = lval[k];
      cand_j[row * CAP + k] = lidx[k];
    }
    if (t == 0) { cntc[row] = c; Trow[row] = T; }
  }
}

// ===========================================================================
// K2: block 0 = exact median (radix select, parallel bin scan);
//     blocks [1,513) = fused SpMM0+ReLU+GEMM1, 8 rows/block:
//       h1[i] = relu(dvi*(dvi*Y0[i] + sum_j dvj*Y0[j]) + b0)   (LDS only)
//       Y1[i] = h1[i] @ W1
// ===========================================================================
__global__ __launch_bounds__(256) void K2(const float* __restrict__ r16, float* __restrict__ scal,
                                          const float* __restrict__ Y0, const int* __restrict__ cnt1,
                                          const int* __restrict__ nbr1, const float* __restrict__ b0,
                                          const float* __restrict__ W1, float* __restrict__ Y1) {
  int b = blockIdx.x, t = threadIdx.x;
  if (b == 0) {
    __shared__ unsigned int keys[N];
    __shared__ int hist[256];
    __shared__ int wsum4[4];
    __shared__ unsigned int s_prefix;
    __shared__ int s_rank;
#pragma unroll
    for (int q = 0; q < 16; q++) keys[q * 256 + t] = __float_as_uint(r16[q * 256 + t]);
    __syncthreads();
    float res[2];
#pragma unroll
    for (int sel = 0; sel < 2; sel++) {
      if (t == 0) { s_rank = 2047 + sel; s_prefix = 0u; }
      __syncthreads();
      unsigned int mask = 0u;
      for (int shift = 24; shift >= 0; shift -= 8) {
        hist[t] = 0;
        __syncthreads();
        unsigned int prefix = s_prefix;
#pragma unroll
        for (int q = 0; q < 16; q++) {
          unsigned int k = keys[q * 256 + t];
          if ((k & mask) == prefix) atomicAdd(&hist[(k >> shift) & 255], 1);
        }
        __syncthreads();
        int r = s_rank;
        int ht = hist[t];
        int x = ht;
#pragma unroll
        for (int s = 1; s < 64; s <<= 1) {
          int y = __shfl_up(x, s, 64);
          if ((t & 63) >= s) x += y;
        }
        if ((t & 63) == 63) wsum4[t >> 6] = x;
        __syncthreads();
        int off = 0;
#pragma unroll
        for (int w = 0; w < 4; w++) off += (w < (t >> 6)) ? wsum4[w] : 0;
        int incl = x + off, excl = incl - ht;
        if (r >= excl && r < incl) {          // exactly one thread
          s_prefix = prefix | ((unsigned int)t << shift);
          s_rank = r - excl;
        }
        __syncthreads();
        mask |= (255u << shift);
      }
      res[sel] = __uint_as_float(s_prefix);
      __syncthreads();
    }
    if (t == 0) {
      float dcut = 0.5f * (res[0] + res[1]);
      scal[0] = dcut;
      scal[1] = 1.0f / dcut;
    }
  } else {
    __shared__ float xs[8][128];
    int g = b - 1;            // 0..511
    int r0 = g * 8;
    int col = t & 127, half = t >> 7;
    // SpMM0 + bias + relu for 4 rows per half, h1 kept in LDS only
#pragma unroll
    for (int r = 0; r < 4; r++) {
      int row = r0 + half * 4 + r;
      int ci = min(cnt1[row], CAP);
      float dvi = 1.0f / sqrtf((float)ci + 1.0f);
      const int* lst = nbr1 + row * CAP;
      float acc = dvi * Y0[(size_t)row * 128 + col];
      for (int q = 0; q < ci; q++) {
        int j = lst[q];
        float dvj = 1.0f / sqrtf((float)min(cnt1[j], CAP) + 1.0f);
        acc += dvj * Y0[(size_t)j * 128 + col];
      }
      xs[half * 4 + r][col] = fmaxf(dvi * acc + b0[col], 0.0f);
    }
    __syncthreads();
    float acc2[4] = {0.f, 0.f, 0.f, 0.f};
#pragma unroll 4
    for (int k = 0; k < 128; k++) {
      float wk = W1[k * 128 + col];
#pragma unroll
      for (int r = 0; r < 4; r++) acc2[r] = fmaf(xs[half * 4 + r][k], wk, acc2[r]);
    }
#pragma unroll
    for (int r = 0; r < 4; r++) Y1[(size_t)(r0 + half * 4 + r) * 128 + col] = acc2[r];
  }
}

// ===========================================================================
// K4: SpMM1 (no relu) -> h, plus row norms. 2 rows/block.
// ===========================================================================
__global__ __launch_bounds__(256) void K4(const float* __restrict__ Y1, const int* __restrict__ cnt1,
                                          const int* __restrict__ nbr1, const float* __restrict__ b1,
                                          float* __restrict__ hbuf, float* __restrict__ hnorm) {
  __shared__ float red[4];
  int b = blockIdx.x, t = threadIdx.x;
  int row = 2 * b + (t >> 7);
  int col = t & 127;
  int ci = min(cnt1[row], CAP);
  float dvi = 1.0f / sqrtf((float)ci + 1.0f);
  const int* lst = nbr1 + row * CAP;
  float acc = dvi * Y1[(size_t)row * 128 + col];
  for (int q = 0; q < ci; q++) {
    int j = lst[q];
    float dvj = 1.0f / sqrtf((float)min(cnt1[j], CAP) + 1.0f);
    acc += dvj * Y1[(size_t)j * 128 + col];
  }
  float h = dvi * acc + b1[col];
  hbuf[(size_t)row * 128 + col] = h;
  float ss = h * h;
#pragma unroll
  for (int s = 32; s; s >>= 1) ss += __shfl_xor(ss, s, 64);
  if ((t & 63) == 0) red[t >> 6] = ss;
  __syncthreads();
  if (t == 0)   hnorm[row] = sqrtf(red[0] + red[1]);
  if (t == 128) hnorm[row] = sqrtf(red[2] + red[3]);
}

// ===========================================================================
// K5: per row: filter candidates by (d>0 && d<=dcut), s_d = 0.5*exp(-8(d/dcut)^2),
//     s1 = 0.5*relu(cos(h_i,h_j)); write s[i,j] directly (outputs pre-zeroed);
//     save (j,val) lists + deg[i] for K6's s_norm scatter.
//     Slow path (never taken on this data): rescan dis row if Trow < dcut.
// ===========================================================================
__global__ __launch_bounds__(256) void K5(const float* __restrict__ dis, const float* __restrict__ scal,
                                          const float* __restrict__ cand_d, const int* __restrict__ cand_j,
                                          const int* __restrict__ cntc, const float* __restrict__ Trow,
                                          const float* __restrict__ hbuf, const float* __restrict__ hnorm,
                                          float* __restrict__ vals, int* __restrict__ jdx,
                                          int* __restrict__ cnt2, float* __restrict__ deg,
                                          float* __restrict__ s_out) {
  __shared__ float cd[CAP];
  __shared__ int cj[CAP];
  __shared__ float sdv[CAP];
  __shared__ int sj[CAP];
  __shared__ int ccnt, scnt;
  __shared__ float hi[128];
  __shared__ float wred[4];
  int row = blockIdx.x, t = threadIdx.x;
  int wv = t >> 6, ln = t & 63;
  float dcut = scal[0];
  if (t == 0) { scnt = 0; ccnt = 0; }
  if (t < 128) hi[t] = hbuf[(size_t)row * 128 + t];
  __syncthreads();
  int c1;
  if (Trow[row] >= dcut) {
    c1 = cntc[row];
    for (int k = t; k < c1; k += 256) { cd[k] = cand_d[row * CAP + k]; cj[k] = cand_j[row * CAP + k]; }
  } else {
    const float4* dp = (const float4*)(dis + (size_t)row * N);
#pragma unroll
    for (int q = 0; q < 4; q++) {
      float4 d = dp[q * 256 + t];
      int jb = (q * 256 + t) << 2;
      if (d.x <= dcut) { int p = atomicAdd(&ccnt, 1); if (p < CAP) { cd[p] = d.x; cj[p] = jb + 0; } }
      if (d.y <= dcut) { int p = atomicAdd(&ccnt, 1); if (p < CAP) { cd[p] = d.y; cj[p] = jb + 1; } }
      if (d.z <= dcut) { int p = atomicAdd(&ccnt, 1); if (p < CAP) { cd[p] = d.z; cj[p] = jb + 2; } }
      if (d.w <= dcut) { int p = atomicAdd(&ccnt, 1); if (p < CAP) { cd[p] = d.w; cj[p] = jb + 3; } }
    }
    __syncthreads();
    c1 = min(ccnt, CAP);
  }
  __syncthreads();
  if (t < c1) {
    float d = cd[t];
    if (d > 0.f && d <= dcut) {
      float r = d / dcut;
      int p = atomicAdd(&scnt, 1);
      sdv[p] = 0.5f * expf(-8.0f * r * r);
      sj[p] = cj[t];
    }
  }
  __syncthreads();
  int c2 = scnt;
  float ni = hnorm[row];
  float wsum = 0.f;
  for (int idx = wv; idx < c2; idx += 4) {
    int j = sj[idx];
    const float* hj = hbuf + (size_t)j * 128;
    float p = hi[ln] * hj[ln] + hi[ln + 64] * hj[ln + 64];
#pragma unroll
    for (int s = 32; s; s >>= 1) p += __shfl_xor(p, s, 64);
    if (ln == 0) {
      float s1 = fmaxf(p / (ni * hnorm[j] + 1e-8f), 0.f);
      float v = sdv[idx] + 0.5f * s1;
      s_out[(size_t)row * N + j] = v;          // second output, pre-zeroed
      vals[row * CAP + idx] = v;
      jdx[row * CAP + idx] = j;
      wsum += v;
    }
  }
  if (ln == 0) wred[wv] = wsum;
  __syncthreads();
  if (t == 0) {
    deg[row] = wred[0] + wred[1] + wred[2] + wred[3];
    cnt2[row] = c2;
  }
}

// ===========================================================================
// K6: scatter s_norm[i,j] = dinv_i * dinv_j * v (outputs pre-zeroed).
// ===========================================================================
__global__ __launch_bounds__(128) void K6(const float* __restrict__ vals, const int* __restrict__ jdx,
                                          const int* __restrict__ cnt2, const float* __restrict__ deg,
                                          float* __restrict__ s_norm_out) {
  int row = blockIdx.x, t = threadIdx.x;
  int c2 = cnt2[row];
  if (t < c2) {
    float dgi = deg[row];
    float di = (dgi > 0.f) ? (1.0f / sqrtf(dgi)) : 0.f;
    int j = jdx[row * CAP + t];
    float v = vals[row * CAP + t];
    float dgj = deg[j];
    float dj = (dgj > 0.f) ? (1.0f / sqrtf(dgj)) : 0.f;
    s_norm_out[(size_t)row * N + j] = di * dj * v;
  }
}

extern "C" void kernel_launch(void* const* d_in, const int* in_sizes, int n_in,
                              void* d_out, int out_size, void* d_ws, size_t ws_size,
                              hipStream_t stream) {
  const float* features = (const float*)d_in[0];
  const float* adj      = (const float*)d_in[1];
  const float* dis      = (const float*)d_in[2];
  const float* W0       = (const float*)d_in[3];
  const float* b0       = (const float*)d_in[4];
  const float* W1       = (const float*)d_in[5];
  const float* b1       = (const float*)d_in[6];
  float* out    = (float*)d_out;              // s_norm
  float* s_half = out + (size_t)N * N;        // s

  char* ws = (char*)d_ws;
  float* r16   = (float*)(ws + 0);            // 16KB
  int*   cnt1  = (int*)  (ws + 16384);        // 16KB
  int*   cntc  = (int*)  (ws + 32768);        // 16KB
  float* Trow  = (float*)(ws + 49152);        // 16KB
  float* deg   = (float*)(ws + 65536);        // 16KB
  int*   cnt2  = (int*)  (ws + 81920);        // 16KB
  float* scal  = (float*)(ws + 98304);        // small
  float* hnorm = (float*)(ws + 114688);       // 16KB
  int*   nbr1  = (int*)  (ws + 131072 + 0 * 2097152);
  float* cand_dv=(float*)(ws + 131072 + 1 * 2097152);
  int*   cand_j= (int*)  (ws + 131072 + 2 * 2097152);
  float* vals  = (float*)(ws + 131072 + 3 * 2097152);
  int*   jdx   = (int*)  (ws + 131072 + 4 * 2097152);
  float* Y0    = (float*)(ws + 131072 + 5 * 2097152);
  float* Y1    = (float*)(ws + 131072 + 6 * 2097152);
  float* hbuf  = (float*)(ws + 131072 + 7 * 2097152);

  // zero both dense outputs via the runtime fill path (~6 TB/s) + cnt1
  hipMemsetAsync(out, 0, (size_t)2 * N * N * sizeof(float), stream);
  hipMemsetAsync(cnt1, 0, N * sizeof(int), stream);

  K1<<<5376, 256, 0, stream>>>(dis, (const float4*)adj, features, W0,
                               cnt1, nbr1, r16, cand_dv, cand_j, cntc, Trow, Y0);
  K2<<<513, 256, 0, stream>>>(r16, scal, Y0, cnt1, nbr1, b0, W1, Y1);
  K4<<<2048, 256, 0, stream>>>(Y1, cnt1, nbr1, b1, hbuf, hnorm);
  K5<<<4096, 256, 0, stream>>>(dis, scal, cand_dv, cand_j, cntc, Trow,
                               hbuf, hnorm, vals, jdx, cnt2, deg, s_half);
  K6<<<4096, 128, 0, stream>>>(vals, jdx, cnt2, deg, out);
}